// Round 12
// baseline (333.470 us; speedup 1.0000x reference)
//
#include <hip/hip_runtime.h>
#include <math.h>

#define SAMPLING_EPS 1e-5f
#define TCAND 2.8f          // prefilter threshold for N(0,1) logits; exact-fallback if invalid
#define BLOCK_A 256
#define KF4 5               // float4 per thread in pass1 (25*256*5*4 = 128000 exact)
#define BLOCK_B 256
#define CAPL 2048           // LDS candidate capacity (fallback path)
#define NBIN 4096           // fallback histogram bins (top 12 bits of monotone float)

// monotone float->uint transform (no NaNs expected)
__device__ __forceinline__ unsigned f2u(float f) {
  unsigned b = __float_as_uint(f);
  return (b & 0x80000000u) ? ~b : (b | 0x80000000u);
}

// combine two online-softmax partials: max, sum exp(x-m), sum exp((x-m)/t).
// (m==nm) guards avoid -inf - (-inf) = NaN on degenerate partials.
__device__ __forceinline__ void redCombine(float& m, float& sr, float& ss,
                                           float om, float osr, float oss,
                                           float its) {
  float nm = fmaxf(m, om);
  float e1 = (m == nm) ? 1.0f : __expf(m - nm);
  float e2 = (om == nm) ? 1.0f : __expf(om - nm);
  float f1 = (m == nm) ? 1.0f : __expf((m - nm) * its);
  float f2 = (om == nm) ? 1.0f : __expf((om - nm) * its);
  sr = sr * e1 + osr * e2;
  ss = ss * f1 + oss * f2;
  m = nm;
}

__global__ void __launch_bounds__(BLOCK_A) sampler_pass1(
    const float* __restrict__ logits, const float* __restrict__ temperature,
    float4* __restrict__ partials, unsigned* __restrict__ cnt,
    float* __restrict__ candV, int* __restrict__ candI,
    int V, int cap) {
  const int row = blockIdx.y;
  const int chunk = blockIdx.x;
  const int S = gridDim.x;
  const int tid = threadIdx.x;
  const int f4row = V >> 2;
  const int base = chunk * (BLOCK_A * KF4);
  const float* lr = logits + (size_t)row * V;
  const float4* p4 = reinterpret_cast<const float4*>(lr);

  float temp = temperature[row];
  float ts = (temp < SAMPLING_EPS) ? 1.0f : temp;
  float its = 1.0f / ts;

  // phase 1: register-blocked loads (5 independent coalesced 16B loads)
  float x[KF4 * 4];
  int gj[KF4];
  #pragma unroll
  for (int k = 0; k < KF4; ++k) {
    int j = base + tid + k * BLOCK_A;
    gj[k] = j;
    if (j < f4row) {
      float4 v = p4[j];
      x[4 * k + 0] = v.x; x[4 * k + 1] = v.y;
      x[4 * k + 2] = v.z; x[4 * k + 3] = v.w;
    } else {
      x[4 * k + 0] = -INFINITY; x[4 * k + 1] = -INFINITY;
      x[4 * k + 2] = -INFINITY; x[4 * k + 3] = -INFINITY;
    }
  }

  // phase 2: branchless thread-local max
  float m = -INFINITY;
  #pragma unroll
  for (int e = 0; e < KF4 * 4; ++e) m = fmaxf(m, x[e]);
  float mc = fmaxf(m, -1.0e37f);   // finite shift even for all-OOB threads

  // phase 3: independent dual exp-sums (no branch, no loop-carried exp chain)
  float sr0 = 0.f, sr1 = 0.f, ss0 = 0.f, ss1 = 0.f;
  #pragma unroll
  for (int e = 0; e < KF4 * 4; e += 2) {
    float d0 = x[e] - mc, d1 = x[e + 1] - mc;
    sr0 += __expf(d0);
    sr1 += __expf(d1);
    ss0 += __expf(d0 * its);
    ss1 += __expf(d1 * its);
  }
  float sr = sr0 + sr1, ss = ss0 + ss1;

  // candidate push (rare: ~P(x>2.8) per element; exec-masked atomic)
  #pragma unroll
  for (int k = 0; k < KF4; ++k) {
    #pragma unroll
    for (int e = 0; e < 4; ++e) {
      float xv = x[4 * k + e];
      if (xv > TCAND) {
        unsigned p = atomicAdd(cnt + row, 1u);
        if (p < (unsigned)cap) {
          candV[(size_t)row * cap + p] = xv;
          candI[(size_t)row * cap + p] = (gj[k] << 2) + e;
        }
      }
    }
  }

  // scalar tail for V % 4 != 0 (never taken at V=128000)
  if ((V & 3) && chunk == 0 && tid == 0) {
    for (int i = (f4row << 2); i < V; ++i) {
      float xv = lr[i];
      redCombine(mc, sr, ss, xv, 1.0f, 1.0f, its);
      m = fmaxf(m, xv);
      if (xv > TCAND) {
        unsigned p = atomicAdd(cnt + row, 1u);
        if (p < (unsigned)cap) {
          candV[(size_t)row * cap + p] = xv;
          candI[(size_t)row * cap + p] = i;
        }
      }
    }
  }

  // wave (64-lane) reduction; m (not mc) keeps honest -inf for empty partials
  float mm = (m == -INFINITY) ? -INFINITY : mc;  // mc==m for non-empty threads
  #pragma unroll
  for (int off = 32; off > 0; off >>= 1) {
    float om = __shfl_down(mm, off);
    float osr = __shfl_down(sr, off);
    float oss = __shfl_down(ss, off);
    redCombine(mm, sr, ss, om, osr, oss, its);
  }
  __shared__ float wm[BLOCK_A / 64], wsr[BLOCK_A / 64], wss[BLOCK_A / 64];
  int wave = tid >> 6, lane = tid & 63;
  if (lane == 0) { wm[wave] = mm; wsr[wave] = sr; wss[wave] = ss; }
  __syncthreads();
  if (tid == 0) {
    for (int w = 1; w < BLOCK_A / 64; ++w)
      redCombine(mm, sr, ss, wm[w], wsr[w], wss[w], its);
    partials[row * S + chunk] = make_float4(mm, 0.f, sr, ss);
  }
}

__global__ void __launch_bounds__(BLOCK_B) sampler_finalize(
    const float* __restrict__ logits, const float* __restrict__ temperature,
    const float* __restrict__ top_p, const int* __restrict__ top_k,
    const float* __restrict__ gumbel,
    const float4* __restrict__ partials, const unsigned* __restrict__ cnt,
    const float* __restrict__ candV, const int* __restrict__ candI,
    float* __restrict__ out_ids, float* __restrict__ out_idx,
    float* __restrict__ out_lp, float* __restrict__ out_rank,
    int V, int S, int L, int cap, int NTOP) {
  const int row = blockIdx.x;
  const int tid = threadIdx.x;

  __shared__ float sV[CAPL];
  __shared__ int   sI[CAPL];
  __shared__ float sLp[CAPL];
  __shared__ float sSc[CAPL];
  __shared__ int   hist[NBIN];
  // sampling order (reference: argsort(-scaled), stable)
  __shared__ float posSc[128], posLp[128];
  __shared__ int   posIdx[128];
  // output order (reference: top_k(raw_logprobs))
  __shared__ float topLp[128];
  __shared__ int   topIdx[128];
  __shared__ float gscore[128], pexp[128];
  __shared__ float shM, shSr, shSs, shLpSel;
  __shared__ unsigned uEdge;
  __shared__ int   fcnt;
  __shared__ int   wred[BLOCK_B / 64];

  float temp = temperature[row];
  float ts = (temp < SAMPLING_EPS) ? 1.0f : temp;

  // combine split partials
  if (tid == 0) {
    float m = -INFINITY, sr = 0.f, ss = 0.f;
    float its = 1.0f / ts;
    for (int s = 0; s < S; ++s) {
      float4 p = partials[row * S + s];
      redCombine(m, sr, ss, p.x, p.z, p.w, its);
    }
    shM = m; shSr = sr; shSs = ss;
  }
  __syncthreads();
  const float M = shM;
  const float Ss = shSs;
  const float logSr = logf(shSr);

  // candidate set: fast path (prefiltered gather) or exact histogram fallback
  unsigned c = (cap > 0) ? cnt[row] : 0u;
  int C;
  if (cap > 0 && c >= (unsigned)NTOP && c <= (unsigned)cap) {
    C = (int)c;
    for (int i = tid; i < C; i += BLOCK_B) {
      float v = candV[(size_t)row * cap + i];
      int id = candI[(size_t)row * cap + i];
      sV[i] = v; sI[i] = id;
      sLp[i] = (v - M) - logSr;       // log_softmax (shift-invariant in M)
      sSc[i] = v / ts;                // same op as reference scaled = logits / temp_safe
    }
    __syncthreads();
  } else {
    const float* lr = logits + (size_t)row * V;
    for (int i = tid; i < NBIN; i += BLOCK_B) hist[i] = 0;
    __syncthreads();
    for (int i = tid; i < V; i += BLOCK_B) atomicAdd(&hist[f2u(lr[i]) >> 20], 1);
    __syncthreads();
    if (tid == 0) {
      int acc = 0, eb = 0;
      for (int b = NBIN - 1; b >= 0; --b) { acc += hist[b]; if (acc >= NTOP) { eb = b; break; } }
      uEdge = ((unsigned)eb) << 20;
      fcnt = 0;
    }
    __syncthreads();
    for (int i = tid; i < V; i += BLOCK_B) {
      float x = lr[i];
      if (f2u(x) >= uEdge) {
        int p = atomicAdd(&fcnt, 1);
        if (p < CAPL) { sV[p] = x; sI[p] = i; }
      }
    }
    __syncthreads();
    C = (fcnt < CAPL) ? fcnt : CAPL;
    for (int i = tid; i < C; i += BLOCK_B) {
      float v = sV[i];
      sLp[i] = (v - M) - logSr;
      sSc[i] = v / ts;
    }
    __syncthreads();
  }

  const int NT = (C < NTOP) ? C : NTOP;

  // dual rank-select over candidates:
  //  A) sampling order: (scaled desc, idx asc)  == stable argsort(-scaled)
  //  B) output order:   (logprob desc, idx asc) == lax.top_k(raw_logprobs)
  for (int i = tid; i < C; i += BLOCK_B) {
    float sci = sSc[i], lpi = sLp[i];
    int ii = sI[i];
    int rA = 0, rB = 0;
    for (int j = 0; j < C; ++j) {
      float scj = sSc[j], lpj = sLp[j];
      int ij = sI[j];
      rA += (scj > sci) || (scj == sci && ij < ii);
      rB += (lpj > lpi) || (lpj == lpi && ij < ii);
    }
    if (rA < NT) { posSc[rA] = sci; posLp[rA] = lpi; posIdx[rA] = ii; }
    if (rB < NT) { topLp[rB] = lpi; topIdx[rB] = ii; }
  }
  __syncthreads();

  // per-candidate prob + gumbel score in sampling order
  const float Msc = M / ts;
  if (tid < NT) {
    float sc = posSc[tid];
    gscore[tid] = sc + gumbel[(size_t)row * V + posIdx[tid]];
    pexp[tid] = expf(sc - Msc) / Ss;   // softmax over full V (denominator from pass 1)
  }
  __syncthreads();

  // serial top-p/top-k masked Gumbel-max (NT <= 128 iterations).
  // keep_p replicated as reference: inclusive cumsum then subtract.
  if (tid == 0) {
    int k = top_k[row];
    if (k < 1) k = 1;
    if (k > V) k = V;
    float tp = top_p[row];
    float cum = 0.f, best = -INFINITY;
    int bpos = 0;
    for (int j = 0; j < NT; ++j) {
      float p = pexp[j];
      cum += p;
      if (j < k && (cum - p) <= tp) {        // keep_k & keep_p
        float s = gscore[j];
        if (s > best) { best = s; bpos = j; }  // strict > => first-index argmax
      }
    }
    int sampled; float lpsel;
    if (temp < SAMPLING_EPS) {
      // greedy: argmax(logits) first-occurrence == top output-order entry
      sampled = topIdx[0];
      lpsel = topLp[0];
    } else {
      sampled = posIdx[bpos];
      lpsel = posLp[bpos];
    }
    shLpSel = lpsel;
    out_ids[row] = (float)sampled;
    out_idx[row * (L + 1)] = (float)sampled;
    out_lp[row * (L + 1)] = lpsel;
  }
  __syncthreads();

  // token rank: 1 + count(logprob > selected) — candidate set provably contains
  // every element above the selected one
  float lpsel = shLpSel;
  int cg = 0;
  for (int i = tid; i < C; i += BLOCK_B) cg += (sLp[i] > lpsel) ? 1 : 0;
  for (int off = 32; off > 0; off >>= 1) cg += __shfl_down(cg, off);
  if ((tid & 63) == 0) wred[tid >> 6] = cg;
  __syncthreads();
  if (tid == 0) {
    int t = 0;
    for (int w = 0; w < BLOCK_B / 64; ++w) t += wred[w];
    out_rank[row] = (float)(t + 1);
  }

  // top-L logprobs + indices (output order)
  if (tid < L && tid < NT) {
    out_idx[row * (L + 1) + 1 + tid] = (float)topIdx[tid];
    out_lp[row * (L + 1) + 1 + tid] = topLp[tid];
  }
}

extern "C" void kernel_launch(void* const* d_in, const int* in_sizes, int n_in,
                              void* d_out, int out_size, void* d_ws, size_t ws_size,
                              hipStream_t stream) {
  const float* logits      = (const float*)d_in[0];
  const float* temperature = (const float*)d_in[1];
  const float* top_p       = (const float*)d_in[2];
  const int*   top_k       = (const int*)d_in[3];
  const float* gumbel      = (const float*)d_in[4];

  const int B = in_sizes[1];
  const int V = in_sizes[0] / B;
  int L = out_size / (2 * B) - 2;          // out = B + B(L+1) + B(L+1) + B
  if (L < 0) L = 0;
  int NTOP = 64;
  if (L > 64) NTOP = (L <= 128) ? L : 128;

  const int f4row = V >> 2;
  int S = (f4row + BLOCK_A * KF4 - 1) / (BLOCK_A * KF4);   // 25 for V=128000
  if (S < 1) S = 1;

  // workspace layout: counters | partials | candV | candI
  unsigned char* ws = (unsigned char*)d_ws;
  size_t cntBytes = ((size_t)B * 4 + 255) & ~(size_t)255;
  unsigned* cnt = (unsigned*)ws;
  float4* partials = (float4*)(ws + cntBytes);
  size_t off = cntBytes + (size_t)B * S * sizeof(float4);
  off = (off + 255) & ~(size_t)255;
  size_t rem = (ws_size > off) ? (ws_size - off) : 0;
  int cap = (int)(rem / ((size_t)B * 8));
  if (cap > 1024) cap = 1024;
  if (cap < 0) cap = 0;
  float* candV = (float*)(ws + off);
  int*   candI = (int*)(ws + off + (size_t)B * cap * 4);

  hipMemsetAsync(cnt, 0, (size_t)B * 4, stream);

  dim3 gA(S, B);
  sampler_pass1<<<gA, BLOCK_A, 0, stream>>>(logits, temperature, partials, cnt,
                                            candV, candI, V, cap);

  float* out_f = (float*)d_out;
  float* out_ids = out_f;
  float* out_idx = out_f + B;
  float* out_lp = out_f + B + B * (L + 1);
  float* out_rank = out_f + B + 2 * B * (L + 1);

  sampler_finalize<<<B, BLOCK_B, 0, stream>>>(logits, temperature, top_p, top_k, gumbel,
                                              partials, cnt, candV, candI,
                                              out_ids, out_idx, out_lp, out_rank,
                                              V, S, L, cap, NTOP);
}

// Round 16
// 315.489 us; speedup vs baseline: 1.0570x; 1.0570x over previous
//
#include <hip/hip_runtime.h>
#include <math.h>

#define SAMPLING_EPS 1e-5f
#define TCAND 2.8f          // prefilter threshold for N(0,1) logits; exact-fallback if invalid
#define BLOCK_A 256
#define KF4 5               // float4 per thread per chunk (25*256*5*4 = 128000 exact)
#define BLOCK_B 256
#define CAPL 2048           // LDS candidate capacity (fallback path)
#define NBIN 4096           // fallback histogram bins (top 12 bits of monotone float)

// monotone float->uint transform (no NaNs expected)
__device__ __forceinline__ unsigned f2u(float f) {
  unsigned b = __float_as_uint(f);
  return (b & 0x80000000u) ? ~b : (b | 0x80000000u);
}

#define PUSH_CAND(idx, val)                                        \
  {                                                                \
    unsigned p = atomicAdd(cnt + row, 1u);                         \
    if (p < (unsigned)cap) {                                       \
      candV[(size_t)row * cap + p] = (val);                        \
      candI[(size_t)row * cap + p] = (idx);                        \
    }                                                              \
  }

// ---- kernel 1: per-chunk row max + candidate gather (pure streaming fmax) ----
__global__ void __launch_bounds__(BLOCK_A) sampler_max(
    const float* __restrict__ logits, float* __restrict__ maxp,
    unsigned* __restrict__ cnt, float* __restrict__ candV, int* __restrict__ candI,
    int V, int cap) {
  const int row = blockIdx.y;
  const int chunk = blockIdx.x;
  const int S = gridDim.x;
  const int tid = threadIdx.x;
  const int f4 = V >> 2;
  const int base = chunk * (BLOCK_A * KF4);
  const int end4 = (base + BLOCK_A * KF4 < f4) ? (base + BLOCK_A * KF4) : f4;
  const float* lr = logits + (size_t)row * V;
  const float4* p4 = reinterpret_cast<const float4*>(lr);

  float m = -INFINITY;
  for (int j = base + tid; j < end4; j += BLOCK_A) {
    float4 v = p4[j];
    m = fmaxf(m, fmaxf(fmaxf(v.x, v.y), fmaxf(v.z, v.w)));
    int gb = j << 2;
    if (v.x > TCAND) PUSH_CAND(gb + 0, v.x)
    if (v.y > TCAND) PUSH_CAND(gb + 1, v.y)
    if (v.z > TCAND) PUSH_CAND(gb + 2, v.z)
    if (v.w > TCAND) PUSH_CAND(gb + 3, v.w)
  }
  // scalar tail for V % 4 != 0 (never taken at V=128000)
  if ((V & 3) && chunk == 0 && tid == 0) {
    for (int i = (f4 << 2); i < V; ++i) {
      float xv = lr[i];
      m = fmaxf(m, xv);
      if (xv > TCAND) PUSH_CAND(i, xv)
    }
  }

  #pragma unroll
  for (int off = 32; off > 0; off >>= 1) m = fmaxf(m, __shfl_down(m, off));
  __shared__ float wm[BLOCK_A / 64];
  if ((tid & 63) == 0) wm[tid >> 6] = m;
  __syncthreads();
  if (tid == 0) {
    for (int w = 1; w < BLOCK_A / 64; ++w) m = fmaxf(m, wm[w]);
    maxp[row * S + chunk] = m;
  }
}

// ---- kernel 2: dual exp-sums with globally-known M (branchless, no arrays) ----
__global__ void __launch_bounds__(BLOCK_A) sampler_sums(
    const float* __restrict__ logits, const float* __restrict__ temperature,
    const float* __restrict__ maxp, float2* __restrict__ sums, int V) {
  const int row = blockIdx.y;
  const int chunk = blockIdx.x;
  const int S = gridDim.x;
  const int tid = threadIdx.x;
  const int f4 = V >> 2;
  const int base = chunk * (BLOCK_A * KF4);
  const int end4 = (base + BLOCK_A * KF4 < f4) ? (base + BLOCK_A * KF4) : f4;
  const float* lr = logits + (size_t)row * V;
  const float4* p4 = reinterpret_cast<const float4*>(lr);

  __shared__ float shM;
  if (tid < 64) {                       // wave0 reduces the S max-partials
    float v = (tid < S) ? maxp[row * S + tid] : -INFINITY;
    #pragma unroll
    for (int off = 32; off > 0; off >>= 1) v = fmaxf(v, __shfl_down(v, off));
    if (tid == 0) shM = fmaxf(v, -1.0e37f);   // finite even in degenerate case
  }
  __syncthreads();
  const float M = shM;

  float temp = temperature[row];
  float ts = (temp < SAMPLING_EPS) ? 1.0f : temp;
  float its = 1.0f / ts;

  float sr0 = 0.f, sr1 = 0.f, ss0 = 0.f, ss1 = 0.f;
  for (int j = base + tid; j < end4; j += BLOCK_A) {
    float4 v = p4[j];
    float d0 = v.x - M, d1 = v.y - M, d2 = v.z - M, d3 = v.w - M;
    sr0 += __expf(d0) + __expf(d1);
    sr1 += __expf(d2) + __expf(d3);
    ss0 += __expf(d0 * its) + __expf(d1 * its);
    ss1 += __expf(d2 * its) + __expf(d3 * its);
  }
  float sr = sr0 + sr1, ss = ss0 + ss1;
  if ((V & 3) && chunk == 0 && tid == 0) {
    for (int i = (f4 << 2); i < V; ++i) {
      float d = lr[i] - M;
      sr += __expf(d);
      ss += __expf(d * its);
    }
  }

  #pragma unroll
  for (int off = 32; off > 0; off >>= 1) {
    sr += __shfl_down(sr, off);
    ss += __shfl_down(ss, off);
  }
  __shared__ float wsr[BLOCK_A / 64], wss[BLOCK_A / 64];
  if ((tid & 63) == 0) { wsr[tid >> 6] = sr; wss[tid >> 6] = ss; }
  __syncthreads();
  if (tid == 0) {
    for (int w = 1; w < BLOCK_A / 64; ++w) { sr += wsr[w]; ss += wss[w]; }
    sums[row * S + chunk] = make_float2(sr, ss);
  }
}

// ---- kernel 3: per-row finalize ----
__global__ void __launch_bounds__(BLOCK_B) sampler_finalize(
    const float* __restrict__ logits, const float* __restrict__ temperature,
    const float* __restrict__ top_p, const int* __restrict__ top_k,
    const float* __restrict__ gumbel,
    const float* __restrict__ maxp, const float2* __restrict__ sums,
    const unsigned* __restrict__ cnt,
    const float* __restrict__ candV, const int* __restrict__ candI,
    float* __restrict__ out_ids, float* __restrict__ out_idx,
    float* __restrict__ out_lp, float* __restrict__ out_rank,
    int V, int S, int L, int cap, int NTOP) {
  const int row = blockIdx.x;
  const int tid = threadIdx.x;

  __shared__ float sV[CAPL];
  __shared__ int   sI[CAPL];
  __shared__ float sLp[CAPL];
  __shared__ float sSc[CAPL];
  __shared__ int   hist[NBIN];
  // sampling order (reference: argsort(-scaled), stable)
  __shared__ float posSc[128], posLp[128];
  __shared__ int   posIdx[128];
  // output order (reference: top_k(raw_logprobs))
  __shared__ float topLp[128];
  __shared__ int   topIdx[128];
  __shared__ float gscore[128], pexp[128];
  __shared__ float shM, shSr, shSs, shLpSel;
  __shared__ unsigned uEdge;
  __shared__ int   fcnt;
  __shared__ int   wred[BLOCK_B / 64];

  float temp = temperature[row];
  float ts = (temp < SAMPLING_EPS) ? 1.0f : temp;

  // combine partials: plain fmax / plain add (all chunks used the same M)
  if (tid < 64) {
    float v = (tid < S) ? maxp[row * S + tid] : -INFINITY;
    float a = 0.f, b = 0.f;
    if (tid < S) { float2 s2 = sums[row * S + tid]; a = s2.x; b = s2.y; }
    #pragma unroll
    for (int off = 32; off > 0; off >>= 1) {
      v = fmaxf(v, __shfl_down(v, off));
      a += __shfl_down(a, off);
      b += __shfl_down(b, off);
    }
    if (tid == 0) { shM = fmaxf(v, -1.0e37f); shSr = a; shSs = b; }
  }
  __syncthreads();
  const float M = shM;
  const float Ss = shSs;
  const float logSr = logf(shSr);

  // candidate set: fast path (prefiltered gather) or exact histogram fallback
  unsigned c = (cap > 0) ? cnt[row] : 0u;
  int C;
  if (cap > 0 && c >= (unsigned)NTOP && c <= (unsigned)cap) {
    C = (int)c;
    for (int i = tid; i < C; i += BLOCK_B) {
      float v = candV[(size_t)row * cap + i];
      int id = candI[(size_t)row * cap + i];
      sV[i] = v; sI[i] = id;
      sLp[i] = (v - M) - logSr;       // log_softmax (shift-invariant in M)
      sSc[i] = v / ts;                // same op as reference scaled = logits / temp_safe
    }
    __syncthreads();
  } else {
    const float* lr = logits + (size_t)row * V;
    for (int i = tid; i < NBIN; i += BLOCK_B) hist[i] = 0;
    __syncthreads();
    for (int i = tid; i < V; i += BLOCK_B) atomicAdd(&hist[f2u(lr[i]) >> 20], 1);
    __syncthreads();
    if (tid == 0) {
      int acc = 0, eb = 0;
      for (int b = NBIN - 1; b >= 0; --b) { acc += hist[b]; if (acc >= NTOP) { eb = b; break; } }
      uEdge = ((unsigned)eb) << 20;
      fcnt = 0;
    }
    __syncthreads();
    for (int i = tid; i < V; i += BLOCK_B) {
      float x = lr[i];
      if (f2u(x) >= uEdge) {
        int p = atomicAdd(&fcnt, 1);
        if (p < CAPL) { sV[p] = x; sI[p] = i; }
      }
    }
    __syncthreads();
    C = (fcnt < CAPL) ? fcnt : CAPL;
    for (int i = tid; i < C; i += BLOCK_B) {
      float v = sV[i];
      sLp[i] = (v - M) - logSr;
      sSc[i] = v / ts;
    }
    __syncthreads();
  }

  const int NT = (C < NTOP) ? C : NTOP;

  // dual rank-select over candidates:
  //  A) sampling order: (scaled desc, idx asc)  == stable argsort(-scaled)
  //  B) output order:   (logprob desc, idx asc) == lax.top_k(raw_logprobs)
  for (int i = tid; i < C; i += BLOCK_B) {
    float sci = sSc[i], lpi = sLp[i];
    int ii = sI[i];
    int rA = 0, rB = 0;
    for (int j = 0; j < C; ++j) {
      float scj = sSc[j], lpj = sLp[j];
      int ij = sI[j];
      rA += (scj > sci) || (scj == sci && ij < ii);
      rB += (lpj > lpi) || (lpj == lpi && ij < ii);
    }
    if (rA < NT) { posSc[rA] = sci; posLp[rA] = lpi; posIdx[rA] = ii; }
    if (rB < NT) { topLp[rB] = lpi; topIdx[rB] = ii; }
  }
  __syncthreads();

  // per-candidate prob + gumbel score in sampling order
  const float Msc = M / ts;
  if (tid < NT) {
    float sc = posSc[tid];
    gscore[tid] = sc + gumbel[(size_t)row * V + posIdx[tid]];
    pexp[tid] = expf(sc - Msc) / Ss;   // softmax over full V (denominator from pass 2)
  }
  __syncthreads();

  // serial top-p/top-k masked Gumbel-max (NT <= 128 iterations).
  // keep_p replicated as reference: inclusive cumsum then subtract.
  if (tid == 0) {
    int k = top_k[row];
    if (k < 1) k = 1;
    if (k > V) k = V;
    float tp = top_p[row];
    float cum = 0.f, best = -INFINITY;
    int bpos = 0;
    for (int j = 0; j < NT; ++j) {
      float p = pexp[j];
      cum += p;
      if (j < k && (cum - p) <= tp) {        // keep_k & keep_p
        float s = gscore[j];
        if (s > best) { best = s; bpos = j; }  // strict > => first-index argmax
      }
    }
    int sampled; float lpsel;
    if (temp < SAMPLING_EPS) {
      // greedy: argmax(logits) first-occurrence == top output-order entry
      sampled = topIdx[0];
      lpsel = topLp[0];
    } else {
      sampled = posIdx[bpos];
      lpsel = posLp[bpos];
    }
    shLpSel = lpsel;
    out_ids[row] = (float)sampled;
    out_idx[row * (L + 1)] = (float)sampled;
    out_lp[row * (L + 1)] = lpsel;
  }
  __syncthreads();

  // token rank: 1 + count(logprob > selected) — candidate set provably contains
  // every element above the selected one
  float lpsel = shLpSel;
  int cg = 0;
  for (int i = tid; i < C; i += BLOCK_B) cg += (sLp[i] > lpsel) ? 1 : 0;
  #pragma unroll
  for (int off = 32; off > 0; off >>= 1) cg += __shfl_down(cg, off);
  if ((tid & 63) == 0) wred[tid >> 6] = cg;
  __syncthreads();
  if (tid == 0) {
    int t = 0;
    for (int w = 0; w < BLOCK_B / 64; ++w) t += wred[w];
    out_rank[row] = (float)(t + 1);
  }

  // top-L logprobs + indices (output order)
  if (tid < L && tid < NT) {
    out_idx[row * (L + 1) + 1 + tid] = (float)topIdx[tid];
    out_lp[row * (L + 1) + 1 + tid] = topLp[tid];
  }
}

extern "C" void kernel_launch(void* const* d_in, const int* in_sizes, int n_in,
                              void* d_out, int out_size, void* d_ws, size_t ws_size,
                              hipStream_t stream) {
  const float* logits      = (const float*)d_in[0];
  const float* temperature = (const float*)d_in[1];
  const float* top_p       = (const float*)d_in[2];
  const int*   top_k       = (const int*)d_in[3];
  const float* gumbel      = (const float*)d_in[4];

  const int B = in_sizes[1];
  const int V = in_sizes[0] / B;
  int L = out_size / (2 * B) - 2;          // out = B + B(L+1) + B(L+1) + B
  if (L < 0) L = 0;
  int NTOP = 64;
  if (L > 64) NTOP = (L <= 128) ? L : 128;

  const int f4row = V >> 2;
  int S = (f4row + BLOCK_A * KF4 - 1) / (BLOCK_A * KF4);   // 25 for V=128000
  if (S < 1) S = 1;

  // workspace layout: counters | maxp | sums | candV | candI
  unsigned char* ws = (unsigned char*)d_ws;
  size_t cntBytes = ((size_t)B * 4 + 255) & ~(size_t)255;
  unsigned* cnt = (unsigned*)ws;
  float* maxp = (float*)(ws + cntBytes);
  size_t off = cntBytes + (size_t)B * S * sizeof(float);
  off = (off + 255) & ~(size_t)255;
  float2* sums = (float2*)(ws + off);
  off += (size_t)B * S * sizeof(float2);
  off = (off + 255) & ~(size_t)255;
  size_t rem = (ws_size > off) ? (ws_size - off) : 0;
  int cap = (int)(rem / ((size_t)B * 8));
  if (cap > 1024) cap = 1024;
  if (cap < 0) cap = 0;
  float* candV = (float*)(ws + off);
  int*   candI = (int*)(ws + off + (size_t)B * cap * 4);

  hipMemsetAsync(cnt, 0, (size_t)B * 4, stream);

  dim3 g(S, B);
  sampler_max<<<g, BLOCK_A, 0, stream>>>(logits, maxp, cnt, candV, candI, V, cap);
  sampler_sums<<<g, BLOCK_A, 0, stream>>>(logits, temperature, maxp, sums, V);

  float* out_f = (float*)d_out;
  float* out_ids = out_f;
  float* out_idx = out_f + B;
  float* out_lp = out_f + B + B * (L + 1);
  float* out_rank = out_f + B + 2 * B * (L + 1);

  sampler_finalize<<<B, BLOCK_B, 0, stream>>>(logits, temperature, top_p, top_k, gumbel,
                                              maxp, sums, cnt, candV, candI,
                                              out_ids, out_idx, out_lp, out_rank,
                                              V, S, L, cap, NTOP);
}